// Round 1
// baseline (606.842 us; speedup 1.0000x reference)
//
#include <hip/hip_runtime.h>
#include <stdint.h>

typedef float f32x4 __attribute__((ext_vector_type(4)));
typedef long i64;

#define HID 768
#define UNITS 768
#define BM 32
#define LDS_STRIDE 784      /* 768 + 16-byte pad: 2-way LDS conflicts only (free) */
#define NFRAG 12            /* n-frags per wave: 12*16 = 192 cols */
#define KK_STEPS 24         /* 768 / 32 */
#define NPKT (48 * 24)      /* n-frag tiles * k-steps */

// ---------- fp8 e4m3fn conversion (RNE, saturating) ----------
__device__ __forceinline__ uint8_t f32_to_e4m3_sw(float x) {
    uint32_t u;
    __builtin_memcpy(&u, &x, 4);
    uint32_t sign = (u >> 24) & 0x80u;
    uint32_t a = u & 0x7fffffffu;
    if (a > 0x43e00000u) return (uint8_t)(sign | 0x7e);      // >448: saturate
    if (a < 0x3c800000u) {                                   // < 2^-6: subnormal
        float s;
        __builtin_memcpy(&s, &a, 4);
        int q = (int)rintf(s * 512.0f);                      // exact scale, single RNE
        return (uint8_t)(sign | (uint32_t)q);                // q==8 -> 0x08 == 2^-6
    }
    uint32_t e = a >> 23;
    uint32_t m = a & 0x7fffffu;
    uint32_t mant = m >> 20;
    uint32_t rest = m & 0xfffffu;
    mant += (rest > 0x80000u) || (rest == 0x80000u && (mant & 1u));
    uint32_t te = e - 127u + 7u;
    if (mant == 8u) { mant = 0u; te += 1u; }
    return (uint8_t)(sign | (te << 3) | mant);
}

__device__ __forceinline__ uint32_t pack4_e4m3(float a, float b, float c, float d) {
#if __has_builtin(__builtin_amdgcn_cvt_pk_fp8_f32)
    int v = 0;
    v = __builtin_amdgcn_cvt_pk_fp8_f32(a, b, v, false);     // bytes 0,1
    v = __builtin_amdgcn_cvt_pk_fp8_f32(c, d, v, true);      // bytes 2,3
    return (uint32_t)v;
#else
    return (uint32_t)f32_to_e4m3_sw(a) | ((uint32_t)f32_to_e4m3_sw(b) << 8) |
           ((uint32_t)f32_to_e4m3_sw(c) << 16) | ((uint32_t)f32_to_e4m3_sw(d) << 24);
#endif
}

// ---------- kernel 1: quantize + frag-pack weights ----------
// Packet p = fn*KK_STEPS + kk. Byte offset p*512 + lane*8 holds
// B[k][n] for n = fn*16 + (lane&15), k = kk*32 + (lane>>4)*8 + j  (j = byte 0..7)
__global__ void pack_b_kernel(const float* __restrict__ K, uint8_t* __restrict__ Bp) {
    const int lane = threadIdx.x & 63;
    const int wid = (int)((blockIdx.x * blockDim.x + threadIdx.x) >> 6);
    if (wid >= NPKT) return;
    const int fn = wid / KK_STEPS, kk = wid % KK_STEPS;
    const int n = fn * 16 + (lane & 15);
    const int k0 = kk * 32 + (lane >> 4) * 8;
    float v[8];
#pragma unroll
    for (int j = 0; j < 8; ++j) v[j] = K[(size_t)(k0 + j) * UNITS + n];
    uint2 pr;
    pr.x = pack4_e4m3(v[0], v[1], v[2], v[3]);
    pr.y = pack4_e4m3(v[4], v[5], v[6], v[7]);
    *(uint2*)(Bp + ((size_t)wid << 9) + (size_t)lane * 8) = pr;
}

// ---------- kernel 2: fused LN + fp8 quantize + GEMM + bias ----------
__global__ __launch_bounds__(256, 2)
void fused_ln_gemm(const float* __restrict__ x,
                   const float* __restrict__ gamma,
                   const float* __restrict__ beta,
                   const uint8_t* __restrict__ Bp,
                   const float* __restrict__ bias,
                   float* __restrict__ out) {
    __shared__ uint8_t Alds[BM * LDS_STRIDE];
    const int tid = threadIdx.x;
    const int lane = tid & 63;
    const int wave = tid >> 6;
    const int row0 = blockIdx.x * BM;

    // ---- Phase A: LayerNorm + quantize 8 rows per wave into LDS ----
    for (int rr = 0; rr < 8; ++rr) {
        const int row = wave * 8 + rr;
        const float4* xr = (const float4*)(x + (size_t)(row0 + row) * HID);
        float4 v[3];
        float s = 0.f, s2 = 0.f;
#pragma unroll
        for (int i = 0; i < 3; ++i) {
            v[i] = xr[i * 64 + lane];
            s  += v[i].x + v[i].y + v[i].z + v[i].w;
            s2 += v[i].x * v[i].x + v[i].y * v[i].y + v[i].z * v[i].z + v[i].w * v[i].w;
        }
#pragma unroll
        for (int off = 32; off; off >>= 1) {
            s  += __shfl_xor(s, off);
            s2 += __shfl_xor(s2, off);
        }
        const float mu = s * (1.0f / HID);
        const float var = fmaxf(s2 * (1.0f / HID) - mu * mu, 0.0f);
        const float rs = rsqrtf(var + 1e-5f);
#pragma unroll
        for (int i = 0; i < 3; ++i) {
            const int c4 = i * 64 + lane;             // float4 index along the row
            const float4 g  = ((const float4*)gamma)[c4];
            const float4 bb = ((const float4*)beta)[c4];
            const float y0 = (v[i].x - mu) * rs * g.x + bb.x;
            const float y1 = (v[i].y - mu) * rs * g.y + bb.y;
            const float y2 = (v[i].z - mu) * rs * g.z + bb.z;
            const float y3 = (v[i].w - mu) * rs * g.w + bb.w;
            *(uint32_t*)&Alds[row * LDS_STRIDE + c4 * 4] = pack4_e4m3(y0, y1, y2, y3);
        }
    }
    __syncthreads();

    // ---- Phase B: fp8 MFMA GEMM; wave covers cols [wave*192, +192) ----
    const int nl = lane & 15, quad = lane >> 4;
    f32x4 acc[2][NFRAG];
#pragma unroll
    for (int mf = 0; mf < 2; ++mf)
#pragma unroll
        for (int f = 0; f < NFRAG; ++f) acc[mf][f] = (f32x4){0.f, 0.f, 0.f, 0.f};

    const uint8_t* a0p = &Alds[nl * LDS_STRIDE + quad * 8];
    const uint8_t* a1p = a0p + 16 * LDS_STRIDE;
    const i64* Bq = (const i64*)Bp;
    const int fn0 = wave * NFRAG;

#pragma unroll 2
    for (int kk = 0; kk < KK_STEPS; ++kk) {
        const i64 a0 = *(const i64*)(a0p + kk * 32);
        const i64 a1 = *(const i64*)(a1p + kk * 32);
#pragma unroll
        for (int f = 0; f < NFRAG; ++f) {
            const i64 b = Bq[(size_t)((fn0 + f) * KK_STEPS + kk) * 64 + lane];
            acc[0][f] = __builtin_amdgcn_mfma_f32_16x16x32_fp8_fp8(a0, b, acc[0][f], 0, 0, 0);
            acc[1][f] = __builtin_amdgcn_mfma_f32_16x16x32_fp8_fp8(a1, b, acc[1][f], 0, 0, 0);
        }
    }

    // ---- Epilogue: + bias, store fp32 ----
#pragma unroll
    for (int f = 0; f < NFRAG; ++f) {
        const int col = wave * 192 + f * 16 + nl;
        const float bv = bias[col];
#pragma unroll
        for (int mf = 0; mf < 2; ++mf) {
            const int row = row0 + mf * 16 + quad * 4;
            float* o = out + (size_t)row * UNITS + col;
            o[0 * UNITS] = acc[mf][f][0] + bv;
            o[1 * UNITS] = acc[mf][f][1] + bv;
            o[2 * UNITS] = acc[mf][f][2] + bv;
            o[3 * UNITS] = acc[mf][f][3] + bv;
        }
    }
}

extern "C" void kernel_launch(void* const* d_in, const int* in_sizes, int n_in,
                              void* d_out, int out_size, void* d_ws, size_t ws_size,
                              hipStream_t stream) {
    const float* x     = (const float*)d_in[0];
    const float* gamma = (const float*)d_in[1];
    const float* beta  = (const float*)d_in[2];
    const float* kern  = (const float*)d_in[3];
    const float* bias  = (const float*)d_in[4];
    float* out = (float*)d_out;
    uint8_t* Bp = (uint8_t*)d_ws;   // needs 48*24*512 = 589824 bytes
    const int tokens = in_sizes[0] / HID;

    hipLaunchKernelGGL(pack_b_kernel, dim3((NPKT * 64 + 255) / 256), dim3(256), 0, stream,
                       kern, Bp);
    hipLaunchKernelGGL(fused_ln_gemm, dim3(tokens / BM), dim3(256), 0, stream,
                       x, gamma, beta, Bp, bias, out);
}

// Round 2
// 408.187 us; speedup vs baseline: 1.4867x; 1.4867x over previous
//
#include <hip/hip_runtime.h>
#include <stdint.h>

typedef float f32x4 __attribute__((ext_vector_type(4)));
typedef long i64;

#define HID 768
#define UNITS 768
#define BM 64               /* rows per block */
#define BN 384              /* cols per block (2 n-halves) */
#define LDS_STRIDE 776      /* 768 + 8 pad: <=2-way LDS aliasing on ds_read_b64 */
#define NFRAG 6             /* n-frags per wave: 6*16 = 96 cols */
#define MFRAG 4             /* m-frags per wave: 4*16 = 64 rows */
#define KK_STEPS 24         /* 768 / 32 */
#define NPKT (48 * 24)      /* n-frag tiles * k-steps */

// ---------- fp8 e4m3fn conversion (RNE, saturating) ----------
__device__ __forceinline__ uint8_t f32_to_e4m3_sw(float x) {
    uint32_t u;
    __builtin_memcpy(&u, &x, 4);
    uint32_t sign = (u >> 24) & 0x80u;
    uint32_t a = u & 0x7fffffffu;
    if (a > 0x43e00000u) return (uint8_t)(sign | 0x7e);      // >448: saturate
    if (a < 0x3c800000u) {                                   // < 2^-6: subnormal
        float s;
        __builtin_memcpy(&s, &a, 4);
        int q = (int)rintf(s * 512.0f);
        return (uint8_t)(sign | (uint32_t)q);
    }
    uint32_t e = a >> 23;
    uint32_t m = a & 0x7fffffu;
    uint32_t mant = m >> 20;
    uint32_t rest = m & 0xfffffu;
    mant += (rest > 0x80000u) || (rest == 0x80000u && (mant & 1u));
    uint32_t te = e - 127u + 7u;
    if (mant == 8u) { mant = 0u; te += 1u; }
    return (uint8_t)(sign | (te << 3) | mant);
}

__device__ __forceinline__ uint32_t pack4_e4m3(float a, float b, float c, float d) {
#if __has_builtin(__builtin_amdgcn_cvt_pk_fp8_f32)
    int v = 0;
    v = __builtin_amdgcn_cvt_pk_fp8_f32(a, b, v, false);     // bytes 0,1
    v = __builtin_amdgcn_cvt_pk_fp8_f32(c, d, v, true);      // bytes 2,3
    return (uint32_t)v;
#else
    return (uint32_t)f32_to_e4m3_sw(a) | ((uint32_t)f32_to_e4m3_sw(b) << 8) |
           ((uint32_t)f32_to_e4m3_sw(c) << 16) | ((uint32_t)f32_to_e4m3_sw(d) << 24);
#endif
}

// ---------- kernel 1: quantize + frag-pack weights ----------
// Packet p = fn*KK_STEPS + kk. Byte offset p*512 + lane*8 holds
// B[k][n] for n = fn*16 + (lane&15), k = kk*32 + (lane>>4)*8 + j  (j = byte 0..7)
__global__ void pack_b_kernel(const float* __restrict__ K, uint8_t* __restrict__ Bp) {
    const int lane = threadIdx.x & 63;
    const int wid = (int)((blockIdx.x * blockDim.x + threadIdx.x) >> 6);
    if (wid >= NPKT) return;
    const int fn = wid / KK_STEPS, kk = wid % KK_STEPS;
    const int n = fn * 16 + (lane & 15);
    const int k0 = kk * 32 + (lane >> 4) * 8;
    float v[8];
#pragma unroll
    for (int j = 0; j < 8; ++j) v[j] = K[(size_t)(k0 + j) * UNITS + n];
    uint2 pr;
    pr.x = pack4_e4m3(v[0], v[1], v[2], v[3]);
    pr.y = pack4_e4m3(v[4], v[5], v[6], v[7]);
    *(uint2*)(Bp + ((size_t)wid << 9) + (size_t)lane * 8) = pr;
}

// ---------- kernel 2: fused LN + fp8 quantize + GEMM + bias ----------
__global__ __launch_bounds__(256, 3)
void fused_ln_gemm(const float* __restrict__ x,
                   const float* __restrict__ gamma,
                   const float* __restrict__ beta,
                   const uint8_t* __restrict__ Bp,
                   const float* __restrict__ bias,
                   float* __restrict__ out) {
    __shared__ uint8_t Alds[BM * LDS_STRIDE];
    const int tid = threadIdx.x;
    const int lane = tid & 63;
    const int wave = tid >> 6;
    const int bid = (int)blockIdx.x;
    const int ny = bid & 1;            // n-half fastest: adjacent blocks share x-tile
    const int mt = bid >> 1;
    const int row0 = mt * BM;

    // ---- Phase A: LayerNorm + quantize 16 rows per wave into LDS ----
    for (int rr = 0; rr < BM / 4; ++rr) {
        const int row = wave * (BM / 4) + rr;
        const float4* xr = (const float4*)(x + (size_t)(row0 + row) * HID);
        float4 v[3];
        float s = 0.f, s2 = 0.f;
#pragma unroll
        for (int i = 0; i < 3; ++i) {
            v[i] = xr[i * 64 + lane];
            s  += v[i].x + v[i].y + v[i].z + v[i].w;
            s2 += v[i].x * v[i].x + v[i].y * v[i].y + v[i].z * v[i].z + v[i].w * v[i].w;
        }
#pragma unroll
        for (int off = 32; off; off >>= 1) {
            s  += __shfl_xor(s, off);
            s2 += __shfl_xor(s2, off);
        }
        const float mu = s * (1.0f / HID);
        const float var = fmaxf(s2 * (1.0f / HID) - mu * mu, 0.0f);
        const float rs = rsqrtf(var + 1e-5f);
#pragma unroll
        for (int i = 0; i < 3; ++i) {
            const int c4 = i * 64 + lane;             // float4 index along the row
            const float4 g  = ((const float4*)gamma)[c4];
            const float4 bb = ((const float4*)beta)[c4];
            const float y0 = (v[i].x - mu) * rs * g.x + bb.x;
            const float y1 = (v[i].y - mu) * rs * g.y + bb.y;
            const float y2 = (v[i].z - mu) * rs * g.z + bb.z;
            const float y3 = (v[i].w - mu) * rs * g.w + bb.w;
            *(uint32_t*)&Alds[row * LDS_STRIDE + c4 * 4] = pack4_e4m3(y0, y1, y2, y3);
        }
    }
    __syncthreads();

    // ---- Phase B: fp8 MFMA GEMM; wave covers cols ny*384 + wave*96 .. +96 ----
    const int nl = lane & 15, quad = lane >> 4;
    f32x4 acc[MFRAG][NFRAG];
#pragma unroll
    for (int mf = 0; mf < MFRAG; ++mf)
#pragma unroll
        for (int f = 0; f < NFRAG; ++f) acc[mf][f] = (f32x4){0.f, 0.f, 0.f, 0.f};

    const uint8_t* ap[MFRAG];
#pragma unroll
    for (int mf = 0; mf < MFRAG; ++mf)
        ap[mf] = &Alds[(mf * 16 + nl) * LDS_STRIDE + quad * 8];

    const i64* Bq = (const i64*)Bp;
    const int fn0 = ny * 24 + wave * NFRAG;

    // prefetch kk=0
    i64 bcur[NFRAG];
#pragma unroll
    for (int f = 0; f < NFRAG; ++f)
        bcur[f] = Bq[(size_t)((fn0 + f) * KK_STEPS) * 64 + lane];

#pragma unroll 4
    for (int kk = 0; kk < KK_STEPS; ++kk) {
        // prefetch next k-step's B while MFMAing this one
        const int kn = (kk + 1 < KK_STEPS) ? kk + 1 : kk;
        i64 bnxt[NFRAG];
#pragma unroll
        for (int f = 0; f < NFRAG; ++f)
            bnxt[f] = Bq[(size_t)((fn0 + f) * KK_STEPS + kn) * 64 + lane];

        i64 a[MFRAG];
#pragma unroll
        for (int mf = 0; mf < MFRAG; ++mf)
            a[mf] = *(const i64*)(ap[mf] + kk * 32);

#pragma unroll
        for (int f = 0; f < NFRAG; ++f)
#pragma unroll
            for (int mf = 0; mf < MFRAG; ++mf)
                acc[mf][f] = __builtin_amdgcn_mfma_f32_16x16x32_fp8_fp8(a[mf], bcur[f], acc[mf][f], 0, 0, 0);

#pragma unroll
        for (int f = 0; f < NFRAG; ++f) bcur[f] = bnxt[f];
    }

    // ---- Epilogue: + bias, store fp32 ----
#pragma unroll
    for (int f = 0; f < NFRAG; ++f) {
        const int col = ny * BN + wave * 96 + f * 16 + nl;
        const float bv = bias[col];
#pragma unroll
        for (int mf = 0; mf < MFRAG; ++mf) {
            const int row = row0 + mf * 16 + quad * 4;
            float* o = out + (size_t)row * UNITS + col;
            o[0 * UNITS] = acc[mf][f][0] + bv;
            o[1 * UNITS] = acc[mf][f][1] + bv;
            o[2 * UNITS] = acc[mf][f][2] + bv;
            o[3 * UNITS] = acc[mf][f][3] + bv;
        }
    }
}

extern "C" void kernel_launch(void* const* d_in, const int* in_sizes, int n_in,
                              void* d_out, int out_size, void* d_ws, size_t ws_size,
                              hipStream_t stream) {
    const float* x     = (const float*)d_in[0];
    const float* gamma = (const float*)d_in[1];
    const float* beta  = (const float*)d_in[2];
    const float* kern  = (const float*)d_in[3];
    const float* bias  = (const float*)d_in[4];
    float* out = (float*)d_out;
    uint8_t* Bp = (uint8_t*)d_ws;   // needs 48*24*512 = 589824 bytes
    const int tokens = in_sizes[0] / HID;

    hipLaunchKernelGGL(pack_b_kernel, dim3((NPKT * 64 + 255) / 256), dim3(256), 0, stream,
                       kern, Bp);
    hipLaunchKernelGGL(fused_ln_gemm, dim3((tokens / BM) * 2), dim3(256), 0, stream,
                       x, gamma, beta, Bp, bias, out);
}